// Round 3
// baseline (11850.273 us; speedup 1.0000x reference)
//
#include <hip/hip_runtime.h>

#define B_   1024
#define TE   168
#define TD   24
#define F_   64
#define H_   128
#define H2_  256
#define G_   512
#define KM_  320   // combined [h|c|x] K for m1

// ---- workspace float offsets ----
#define OFF_WMT    0          // [320][128]  rows 0..255 = We^T, 256..319 = Wi^T
#define OFF_VdT    40960      // [128][64]
#define OFF_eWihT  49152      // [64][512]
#define OFF_eWhhT  81920      // [128][512]
#define OFF_mWihT  147456     // [128][512]
#define OFF_mWhhT  212992     // [128][512]
#define OFF_WxT    278528     // [128][128]
#define OFF_WhT    294912     // [256][128]
#define OFF_dWihT  327680     // [128][512]
#define OFF_dWhhT  393216     // [128][512]
#define OFF_ENCB   458752     // [512] bih+bhh
#define OFF_MIDB   459264
#define OFF_DECB   459776
#define OFF_MID    460800                      // [1024][168][128]
#define OFF_WX     (OFF_MID + B_*TE*H_)        // [1024][168][128]
#define OFF_STH    (OFF_WX  + B_*TE*H_)        // [1024][128]
#define OFF_STC    (OFF_STH + B_*H_)
#define WS_FLOATS  (OFF_STC + B_*H_)

__device__ __forceinline__ float fexp2(float x) { return __builtin_amdgcn_exp2f(x); }
__device__ __forceinline__ float frcp(float x)  { return __builtin_amdgcn_rcpf(x); }
#define LOG2E 1.4426950408889634f

__device__ __forceinline__ float sigm(float x) {
    return frcp(1.f + fexp2(-LOG2E * x));
}
__device__ __forceinline__ float tanh_fast(float x) {
    float e = fexp2(2.f * LOG2E * x);
    return 1.f - 2.f * frcp(e + 1.f);
}

// ---------------- prep: transpose weights to [K][N], sum bias pairs ----------------
struct PrepArgs {
    const float *We, *Wi, *Vd, *eWih, *eWhh, *eBih, *eBhh,
                *mWih, *mWhh, *mBih, *mBhh, *Wx, *Wh, *dWih, *dWhh, *dBih, *dBhh;
};

__global__ void prep_kernel(PrepArgs a, float* __restrict__ ws) {
    int sec  = blockIdx.x >> 2;
    int base = (blockIdx.x & 3) * blockDim.x + threadIdx.x;
    const int stride = blockDim.x * 4;
    const float* src = nullptr; int R = 0, C = 0, off = 0;
    switch (sec) {
        case 0:  src = a.We;   R = 128; C = 256; off = OFF_WMT;           break;
        case 1:  src = a.Wi;   R = 128; C = 64;  off = OFF_WMT + 32768;   break;
        case 2:  src = a.Vd;   R = 64;  C = 128; off = OFF_VdT;   break;
        case 3:  src = a.eWih; R = 512; C = 64;  off = OFF_eWihT; break;
        case 4:  src = a.eWhh; R = 512; C = 128; off = OFF_eWhhT; break;
        case 5:  src = a.mWih; R = 512; C = 128; off = OFF_mWihT; break;
        case 6:  src = a.mWhh; R = 512; C = 128; off = OFF_mWhhT; break;
        case 7:  src = a.Wx;   R = 128; C = 128; off = OFF_WxT;   break;
        case 8:  src = a.Wh;   R = 128; C = 256; off = OFF_WhT;   break;
        case 9:  src = a.dWih; R = 512; C = 128; off = OFF_dWihT; break;
        case 10: src = a.dWhh; R = 512; C = 128; off = OFF_dWhhT; break;
        case 11: for (int i = base; i < 512; i += stride) ws[OFF_ENCB + i] = a.eBih[i] + a.eBhh[i]; return;
        case 12: for (int i = base; i < 512; i += stride) ws[OFF_MIDB + i] = a.mBih[i] + a.mBhh[i]; return;
        case 13: for (int i = base; i < 512; i += stride) ws[OFF_DECB + i] = a.dBih[i] + a.dBhh[i]; return;
        default: return;
    }
    int n = R * C;
    int rmask  = R - 1;
    int rshift = (R == 512) ? 9 : ((R == 128) ? 7 : 6);
    for (int o = base; o < n; o += stride) {
        int r = o & rmask, c = o >> rshift;
        ws[off + o] = src[r * C + c];
    }
}

// ---------------- persistent encoder + mid LSTM: 256 blocks x 1024 thr, 4 rows/block ----------------
__global__ __launch_bounds__(1024, 1) void enc_mid_kernel(
    const float* __restrict__ x_all,   // [B][Te][F]
    const float* __restrict__ Wi_b,
    const float* __restrict__ Vd_b,
    const float* __restrict__ Wx_b,
    float* __restrict__ ws)
{
    __shared__ float hcx[4][KM_];     // [h | c | x] per row
    __shared__ float hm[4][H_];
    __shared__ float cm[4][H_];
    __shared__ float xin[4][F_];
    __shared__ float xnext[4][F_];
    __shared__ float av[4][H_];
    __shared__ float avp[8][4][H_];   // m1 k-split partials
    __shared__ float gt[4][G_];
    __shared__ float wxp[2][4][H_];
    __shared__ float bWi[H_], bVd[F_], bWx[H_];
    __shared__ float bE[G_], bM[G_];

    const int tid = threadIdx.x;
    const int b0  = blockIdx.x * 4;

    { int r = tid >> 8, c = tid & 255; hcx[r][c] = 0.f; }
    if (tid < 512) { ((float*)hm)[tid] = 0.f; ((float*)cm)[tid] = 0.f; }
    if (tid < H_) { bWi[tid] = Wi_b[tid]; bWx[tid] = Wx_b[tid]; }
    if (tid < F_) bVd[tid] = Vd_b[tid];
    if (tid < G_) { bE[tid] = ws[OFF_ENCB + tid]; bM[tid] = ws[OFF_MIDB + tid]; }
    if (tid < 256) { // x for t=0
        int r = tid >> 6, f = tid & 63;
        hcx[r][H2_ + f] = x_all[((b0 + r) * TE + 0) * F_ + f];
    }
    __syncthreads();

    const float4* WmT4   = (const float4*)(ws + OFF_WMT);     // [320][128]
    const float*  VdT    = ws + OFF_VdT;                      // [128][64]
    const float2* eWih2  = (const float2*)(ws + OFF_eWihT);   // [64][256]x2
    const float2* eWhh2  = (const float2*)(ws + OFF_eWhhT);   // [128][256]x2
    const float2* mWih2  = (const float2*)(ws + OFF_mWihT);   // [128][256]x2
    const float2* mWhh2  = (const float2*)(ws + OFF_mWhhT);   // [128][256]x2
    const float*  WxT    = ws + OFF_WxT;                      // [128][128]
    float* mid_out = ws + OFF_MID;
    float* wx_out  = ws + OFF_WX;

    for (int t = 0; t < TE; ++t) {
        // P1: m1 partials  av_part = [h|c|x] @ WmT   (k-split x8 across 16 waves)
        {
            int cg = tid & 31, r = (tid >> 5) & 3, ks = tid >> 7;
            int j0 = cg * 4, k0 = ks * 40;
            float a0 = 0.f, a1 = 0.f, a2 = 0.f, a3 = 0.f;
            #pragma unroll 8
            for (int k = k0; k < k0 + 40; ++k) {
                float4 w = WmT4[k * 32 + cg];
                float hv = hcx[r][k];
                a0 += w.x * hv; a1 += w.y * hv; a2 += w.z * hv; a3 += w.w * hv;
            }
            *(float4*)&avp[ks][r][j0] = make_float4(a0, a1, a2, a3);
        }
        __syncthreads();

        // P2: combine partials + bias + tanh; waves 8-11 prefetch x_{t+1}
        if (tid < 512) {
            int r = tid >> 7, j = tid & 127;
            float v = ((avp[0][r][j] + avp[1][r][j]) + (avp[2][r][j] + avp[3][r][j]))
                    + ((avp[4][r][j] + avp[5][r][j]) + (avp[6][r][j] + avp[7][r][j])) + bWi[j];
            av[r][j] = tanh_fast(v);
        } else if (tid < 768) {
            if (t + 1 < TE) {
                int q = tid - 512, r = q >> 6, f = q & 63;
                xnext[r][f] = x_all[((b0 + r) * TE + (t + 1)) * F_ + f];
            }
        }
        __syncthreads();

        // P3: s = av@VdT + bVd; softmax over 64; xin = x * softmax(s)   (one wave per row)
        if (tid < 256) {
            int j = tid & 63, r = tid >> 6;
            float s0 = 0.f, s1 = 0.f, s2 = 0.f, s3 = 0.f;
            #pragma unroll 4
            for (int k = 0; k < H_; k += 4) {
                s0 += VdT[(k    ) * 64 + j] * av[r][k    ];
                s1 += VdT[(k + 1) * 64 + j] * av[r][k + 1];
                s2 += VdT[(k + 2) * 64 + j] * av[r][k + 2];
                s3 += VdT[(k + 3) * 64 + j] * av[r][k + 3];
            }
            float acc = bVd[j] + ((s0 + s1) + (s2 + s3));
            float m = acc;
            for (int off = 32; off > 0; off >>= 1) m = fmaxf(m, __shfl_xor(m, off, 64));
            float e = fexp2((acc - m) * LOG2E);
            float ssum = e;
            for (int off = 32; off > 0; off >>= 1) ssum += __shfl_xor(ssum, off, 64);
            xin[r][j] = hcx[r][H2_ + j] * e * frcp(ssum);
        }
        __syncthreads();

        // P4: enc gates [4][512] = xin@eWihT + h@eWhhT + bE   (2 cols/thread)
        {
            int c2 = tid & 255, r = tid >> 8;
            int j0 = c2 * 2;
            float a0 = bE[j0], a1 = bE[j0 + 1];
            #pragma unroll 8
            for (int k = 0; k < F_; ++k) {
                float2 w = eWih2[k * 256 + c2];
                float xv = xin[r][k];
                a0 += w.x * xv; a1 += w.y * xv;
            }
            #pragma unroll 8
            for (int k = 0; k < H_; ++k) {
                float2 w = eWhh2[k * 256 + c2];
                float hv = hcx[r][k];
                a0 += w.x * hv; a1 += w.y * hv;
            }
            *(float2*)&gt[r][j0] = make_float2(a0, a1);
        }
        __syncthreads();

        // P5: enc LSTM cell; waves 8-11 install prefetched x
        if (tid < 512) {
            int j = tid & 127, r = tid >> 7;
            float gi = gt[r][j], gf = gt[r][j+128], gg = gt[r][j+256], go = gt[r][j+384];
            float c = sigm(gf) * hcx[r][H_ + j] + sigm(gi) * tanh_fast(gg);
            float h = sigm(go) * tanh_fast(c);
            hcx[r][H_ + j] = c; hcx[r][j] = h;
        } else if (tid < 768) {
            if (t + 1 < TE) {
                int q = tid - 512, r = q >> 6, f = q & 63;
                hcx[r][H2_ + f] = xnext[r][f];
            }
        }
        __syncthreads();

        // P6: mid gates [4][512] = h_enc@mWihT + h_mid@mWhhT + bM   (2 cols/thread)
        {
            int c2 = tid & 255, r = tid >> 8;
            int j0 = c2 * 2;
            float a0 = bM[j0], a1 = bM[j0 + 1];
            #pragma unroll 8
            for (int k = 0; k < H_; ++k) {
                float2 w = mWih2[k * 256 + c2];
                float xv = hcx[r][k];
                a0 += w.x * xv; a1 += w.y * xv;
            }
            #pragma unroll 8
            for (int k = 0; k < H_; ++k) {
                float2 w = mWhh2[k * 256 + c2];
                float hv = hm[r][k];
                a0 += w.x * hv; a1 += w.y * hv;
            }
            *(float2*)&gt[r][j0] = make_float2(a0, a1);
        }
        __syncthreads();

        // P7: mid LSTM cell + store mid_out
        if (tid < 512) {
            int j = tid & 127, r = tid >> 7;
            float gi = gt[r][j], gf = gt[r][j+128], gg = gt[r][j+256], go = gt[r][j+384];
            float c = sigm(gf) * cm[r][j] + sigm(gi) * tanh_fast(gg);
            float h = sigm(go) * tanh_fast(c);
            cm[r][j] = c; hm[r][j] = h;
            mid_out[((b0 + r) * TE + t) * H_ + j] = h;
        }
        __syncthreads();

        // P8: wx partials (k-split x2)
        {
            int ks = tid >> 9, q = tid & 511, j = q & 127, r = q >> 7;
            int k0 = ks * 64;
            float s0 = 0.f, s1 = 0.f;
            #pragma unroll 8
            for (int k = k0; k < k0 + 64; k += 2) {
                s0 += WxT[(k    ) * H_ + j] * hm[r][k    ];
                s1 += WxT[(k + 1) * H_ + j] * hm[r][k + 1];
            }
            wxp[ks][r][j] = s0 + s1;
        }
        __syncthreads();

        // P8b: combine + global store (no trailing barrier needed: next P1 touches
        // only avp (last read P2, many barriers ago) and hcx (stable since P5/P6))
        if (tid < 512) {
            int j = tid & 127, r = tid >> 7;
            wx_out[((b0 + r) * TE + t) * H_ + j] = bWx[j] + wxp[0][r][j] + wxp[1][r][j];
        }
    }

    __syncthreads();
    if (tid < 512) {
        int j = tid & 127, r = tid >> 7;
        ws[OFF_STH + (b0 + r) * H_ + j] = hm[r][j];
        ws[OFF_STC + (b0 + r) * H_ + j] = cm[r][j];
    }
}

// ---------------- persistent decoder: 256 blocks x 1024 thr, 4 rows/block ----------------
#define QP_ 132   // padded row stride for qv/qp (kills r-across-lanes bank conflicts)

__global__ __launch_bounds__(1024, 1) void dec_kernel(
    const float* __restrict__ Vw_in,
    const float* __restrict__ Vb_in,
    const float* __restrict__ rw_in,
    const float* __restrict__ rb_in,
    const float* __restrict__ ws,
    float* __restrict__ out)
{
    __shared__ float hc2[4][H2_];      // [hi | ci]
    __shared__ float qv[4][QP_];       // q, then reused as dec_in
    __shared__ float qp[2][4][QP_];    // q k-split partials
    __shared__ float sb[4][TE];
    __shared__ float dinp[8][4][H_];   // dec_in tp-split partials
    __shared__ float gt2[4][G_];
    __shared__ float bD[G_], Vw[H_], rw[H_];

    const int tid = threadIdx.x;
    const int b0  = blockIdx.x * 4;
    const float Vb = Vb_in[0], rb = rb_in[0];

    {
        int r = tid >> 8, c = tid & 255;
        hc2[r][c] = (c < H_) ? ws[OFF_STH + (b0 + r) * H_ + c]
                             : ws[OFF_STC + (b0 + r) * H_ + (c - H_)];
    }
    if (tid < H_) { Vw[tid] = Vw_in[tid]; rw[tid] = rw_in[tid]; }
    if (tid < G_) bD[tid] = ws[OFF_DECB + tid];
    __syncthreads();

    const float*  WhT    = ws + OFF_WhT;                      // [256][128]
    const float2* dWih2  = (const float2*)(ws + OFF_dWihT);   // [128][256]x2
    const float2* dWhh2  = (const float2*)(ws + OFF_dWhhT);   // [128][256]x2
    const float4* wx4    = (const float4*)(ws + OFF_WX);
    const float4* mid4   = (const float4*)(ws + OFF_MID);

    for (int td = 0; td < TD; ++td) {
        // P1: q partials = [hi|ci]@WhT  (k-split x2)
        {
            int ks = tid >> 9, q = tid & 511, j = q & 127, r = q >> 7;
            int k0 = ks * 128;
            float s0 = 0.f, s1 = 0.f;
            #pragma unroll 8
            for (int k = k0; k < k0 + 128; k += 2) {
                s0 += WhT[(k    ) * H_ + j] * hc2[r][k    ];
                s1 += WhT[(k + 1) * H_ + j] * hc2[r][k + 1];
            }
            qp[ks][r][j] = s0 + s1;
        }
        __syncthreads();
        // P1b: combine
        if (tid < 512) {
            int j = tid & 127, r = tid >> 7;
            qv[r][j] = qp[0][r][j] + qp[1][r][j];
        }
        __syncthreads();

        // P2: scores sb[r][tp] = sum_h tanh(q[r][h] + wx[b][tp][h]) * Vw[h] + Vb
        if (tid < 4 * TE) {
            int r = tid & 3, tp = tid >> 2;
            const float4* wxr = wx4 + ((size_t)(b0 + r) * TE + tp) * (H_ / 4);
            float acc = Vb;
            #pragma unroll 8
            for (int kk = 0; kk < H_ / 4; ++kk) {
                float4 w = wxr[kk];
                int j = kk * 4;
                acc += tanh_fast(qv[r][j]     + w.x) * Vw[j];
                acc += tanh_fast(qv[r][j + 1] + w.y) * Vw[j + 1];
                acc += tanh_fast(qv[r][j + 2] + w.z) * Vw[j + 2];
                acc += tanh_fast(qv[r][j + 3] + w.w) * Vw[j + 3];
            }
            sb[r][tp] = acc;
        }
        __syncthreads();

        // P3: dec_in partials over tp chunks of 21
        {
            int ts = tid >> 7, r = (tid >> 5) & 3, cg = tid & 31;
            int t0 = ts * 21;
            float4 a = make_float4(0.f, 0.f, 0.f, 0.f);
            #pragma unroll 3
            for (int tp = t0; tp < t0 + 21; ++tp) {
                float s = sb[r][tp];
                float4 m = mid4[((size_t)(b0 + r) * TE + tp) * 32 + cg];
                a.x += s * m.x; a.y += s * m.y; a.z += s * m.z; a.w += s * m.w;
            }
            *(float4*)&dinp[ts][r][cg * 4] = a;
        }
        __syncthreads();
        // P3b: combine into qv (reused as dec_in)
        if (tid < 512) {
            int j = tid & 127, r = tid >> 7;
            qv[r][j] = ((dinp[0][r][j] + dinp[1][r][j]) + (dinp[2][r][j] + dinp[3][r][j]))
                     + ((dinp[4][r][j] + dinp[5][r][j]) + (dinp[6][r][j] + dinp[7][r][j]));
        }
        __syncthreads();

        // P4: gates [4][512] = dec_in@dWihT + hi@dWhhT + bD   (2 cols/thread)
        {
            int c2 = tid & 255, r = tid >> 8;
            int j0 = c2 * 2;
            float a0 = bD[j0], a1 = bD[j0 + 1];
            #pragma unroll 8
            for (int k = 0; k < H_; ++k) {
                float2 w = dWih2[k * 256 + c2];
                float xv = qv[r][k];
                a0 += w.x * xv; a1 += w.y * xv;
            }
            #pragma unroll 8
            for (int k = 0; k < H_; ++k) {
                float2 w = dWhh2[k * 256 + c2];
                float hv = hc2[r][k];
                a0 += w.x * hv; a1 += w.y * hv;
            }
            *(float2*)&gt2[r][j0] = make_float2(a0, a1);
        }
        __syncthreads();

        // P5: LSTM update
        if (tid < 512) {
            int j = tid & 127, r = tid >> 7;
            float gi = gt2[r][j], gf = gt2[r][j+128], gg = gt2[r][j+256], go = gt2[r][j+384];
            float c = sigm(gf) * hc2[r][H_ + j] + sigm(gi) * tanh_fast(gg);
            float h = sigm(go) * tanh_fast(c);
            hc2[r][H_ + j] = c; hc2[r][j] = h;
        }
        __syncthreads();

        // P6: out[b][td] = h . reg_w + reg_b  (no trailing barrier: next P1 writes qp,
        // last read at P1b many barriers ago; hc2 only read by both P6 and next P1)
        if (tid < 256) {
            int r = tid >> 6, lane = tid & 63;
            float v = hc2[r][lane] * rw[lane] + hc2[r][lane + 64] * rw[lane + 64];
            for (int off = 32; off > 0; off >>= 1) v += __shfl_xor(v, off, 64);
            if (lane == 0) out[(b0 + r) * TD + td] = v + rb;
        }
    }
}

extern "C" void kernel_launch(void* const* d_in, const int* in_sizes, int n_in,
                              void* d_out, int out_size, void* d_ws, size_t ws_size,
                              hipStream_t stream)
{
    (void)in_sizes; (void)n_in; (void)out_size;
    if (ws_size < (size_t)WS_FLOATS * sizeof(float)) return;

    const float* x_all = (const float*)d_in[0];
    const float* Wi_b  = (const float*)d_in[3];
    const float* Vd_b  = (const float*)d_in[6];
    const float* Wx_b  = (const float*)d_in[16];
    const float* V_w   = (const float*)d_in[18];
    const float* V_b   = (const float*)d_in[19];
    const float* reg_w = (const float*)d_in[24];
    const float* reg_b = (const float*)d_in[25];
    float* ws  = (float*)d_ws;
    float* out = (float*)d_out;

    PrepArgs pa{
        (const float*)d_in[4],  // We_w
        (const float*)d_in[2],  // Wi_w
        (const float*)d_in[5],  // Vd_w
        (const float*)d_in[7],  // enc_Wih
        (const float*)d_in[8],  // enc_Whh
        (const float*)d_in[9],  // enc_bih
        (const float*)d_in[10], // enc_bhh
        (const float*)d_in[11], // mid_Wih
        (const float*)d_in[12], // mid_Whh
        (const float*)d_in[13], // mid_bih
        (const float*)d_in[14], // mid_bhh
        (const float*)d_in[15], // Wx_w
        (const float*)d_in[17], // Wh_w
        (const float*)d_in[20], // dec_Wih
        (const float*)d_in[21], // dec_Whh
        (const float*)d_in[22], // dec_bih
        (const float*)d_in[23]  // dec_bhh
    };

    prep_kernel<<<56, 256, 0, stream>>>(pa, ws);
    enc_mid_kernel<<<256, 1024, 0, stream>>>(x_all, Wi_b, Vd_b, Wx_b, ws);
    dec_kernel<<<256, 1024, 0, stream>>>(V_w, V_b, reg_w, reg_b, ws, out);
}